// Round 1
// baseline (1596.150 us; speedup 1.0000x reference)
//
#include <hip/hip_runtime.h>
#include <stdint.h>

#define BATCH 8
#define NCLS 80
#define MAXDET 100
#define CAP 8192
#define NBINS 9216           // 1024 chunks * 9 bins, covers keys 0..9012
#define CHUNKB 9
#define BASEKEY (0x3D4CCCCDu >> 12)   // float bits of 0.05f >> 12

// ---------------- Kernel 1: scores = max softmax prob per row ----------------
__global__ void scores_kernel(const float* __restrict__ cls,
                              float* __restrict__ scores, int BN) {
  int r = blockIdx.x * blockDim.x + threadIdx.x;
  if (r >= BN) return;
  const float4* p = (const float4*)(cls + (size_t)r * NCLS);
  float x[NCLS];
#pragma unroll
  for (int i = 0; i < NCLS / 4; i++) {
    float4 v = p[i];
    x[4 * i] = v.x; x[4 * i + 1] = v.y; x[4 * i + 2] = v.z; x[4 * i + 3] = v.w;
  }
  float m = x[0];
#pragma unroll
  for (int i = 1; i < NCLS; i++) m = fmaxf(m, x[i]);
  // numpy-style pairwise: 8 accumulators over sequential 8-blocks
  float r8[8];
#pragma unroll
  for (int j = 0; j < 8; j++) r8[j] = 0.0f;
#pragma unroll
  for (int i = 0; i < NCLS / 8; i++)
#pragma unroll
    for (int j = 0; j < 8; j++) r8[j] += expf(x[i * 8 + j] - m);
  float s = ((r8[0] + r8[1]) + (r8[2] + r8[3])) + ((r8[4] + r8[5]) + (r8[6] + r8[7]));
  scores[r] = 1.0f / s;
}

// ---------------- Kernel 2: per-batch greedy NMS (1 WG per batch) ----------------
__global__ __launch_bounds__(1024)
void nms_kernel(const float* __restrict__ box, const float* __restrict__ scores,
                uint32_t* __restrict__ pick_idx, uint32_t* __restrict__ pick_ok, int N) {
  __shared__ uint32_t hist[NBINS];
  __shared__ uint32_t partial[1024];
  __shared__ uint32_t cand_sbits[CAP];
  __shared__ uint32_t cand_idx[CAP];
  __shared__ unsigned long long wavemax[16];
  __shared__ unsigned long long gkey_sh;
  __shared__ float pickbox[4];
  __shared__ uint32_t ctr;
  __shared__ int T_sh;

  const int b = blockIdx.x;
  const int tid = threadIdx.x;
  const float* sc = scores + (size_t)b * N;

  for (int i = tid; i < NBINS; i += 1024) hist[i] = 0;
  if (tid == 0) { ctr = 0; T_sh = NBINS; }
  __syncthreads();

  // histogram of score keys (only s >= conf threshold)
  for (int i = tid; i < N; i += 1024) {
    float s = sc[i];
    if (s >= 0.05f) {
      uint32_t key = (__float_as_uint(s) >> 12) - BASEKEY;
      if (key >= NBINS) key = NBINS - 1;
      atomicAdd(&hist[key], 1u);
    }
  }
  __syncthreads();

  // chunk sums + inclusive suffix scan (Hillis-Steele)
  uint32_t psum = 0;
#pragma unroll
  for (int j = 0; j < CHUNKB; j++) psum += hist[tid * CHUNKB + j];
  partial[tid] = psum;
  __syncthreads();
  for (int off = 1; off < 1024; off <<= 1) {
    uint32_t v = partial[tid];
    uint32_t add = (tid + off < 1024) ? partial[tid + off] : 0u;
    __syncthreads();
    partial[tid] = v + add;
    __syncthreads();
  }
  // find minimal bin T with suffix-count <= CAP
  {
    uint32_t St = partial[tid];
    uint32_t Sprev = (tid > 0) ? partial[tid - 1] : 0xFFFFFFFFu;
    if (St <= CAP && (tid == 0 || Sprev > CAP)) {
      int T = 0;
      if (tid != 0) {
        uint32_t cum = St;
        int lo = (tid - 1) * CHUNKB;
        T = lo;
        for (int bb = tid * CHUNKB - 1; bb >= lo; bb--) {
          uint32_t nb = cum + hist[bb];
          if (nb > CAP) { T = bb + 1; break; }
          cum = nb;
          if (bb == lo) T = lo;
        }
      }
      T_sh = T;
    }
  }
  __syncthreads();
  const int T = T_sh;

  // compact candidates (score bits + original index) into LDS
  for (int i = tid; i < N; i += 1024) {
    float s = sc[i];
    if (s >= 0.05f) {
      int key = (int)((__float_as_uint(s) >> 12) - BASEKEY);
      if (key >= T) {
        uint32_t slot = atomicAdd(&ctr, 1u);
        if (slot < CAP) { cand_sbits[slot] = __float_as_uint(s); cand_idx[slot] = i; }
      }
    }
  }
  __syncthreads();
  uint32_t nc = ctr; if (nc > CAP) nc = CAP;

  // distribute candidates to registers: 8 per thread
  const int PC = CAP / 1024;
  float bx[PC][4];
  unsigned long long key[PC];
  uint32_t actmask = 0;
#pragma unroll
  for (int j = 0; j < PC; j++) {
    int slot = tid + j * 1024;
    key[j] = 0ULL;
    bx[j][0] = bx[j][1] = bx[j][2] = bx[j][3] = 0.f;
    if (slot < (int)nc) {
      uint32_t sb = cand_sbits[slot];
      uint32_t idx = cand_idx[slot];
      const float4 f = *(const float4*)(box + ((size_t)b * N + idx) * 4);
      bx[j][0] = f.x; bx[j][1] = f.y; bx[j][2] = f.z - f.x; bx[j][3] = f.w - f.y;
      key[j] = ((unsigned long long)sb << 32) | (unsigned long long)(idx ^ 0xFFFFFFFFu);
      actmask |= (1u << j);
    }
  }

  uint32_t* pidx = pick_idx + b * MAXDET;
  uint32_t* pok  = pick_ok  + b * MAXDET;
  const int wid = tid >> 6, lane = tid & 63;

  for (int m = 0; m < MAXDET; m++) {
    unsigned long long k = 0ULL;
#pragma unroll
    for (int j = 0; j < PC; j++)
      if ((actmask >> j) & 1u) { if (key[j] > k) k = key[j]; }
#pragma unroll
    for (int off = 32; off > 0; off >>= 1) {
      unsigned long long o = __shfl_xor(k, off);
      if (o > k) k = o;
    }
    if (lane == 0) wavemax[wid] = k;
    __syncthreads();
    if (tid == 0) {
      unsigned long long g = 0ULL;
      for (int w = 0; w < 16; w++) if (wavemax[w] > g) g = wavemax[w];
      gkey_sh = g;
    }
    __syncthreads();
    unsigned long long g = gkey_sh;
    if (g == 0ULL) {   // no active candidates: remaining picks are (0, False)
      if (tid == 0) for (int mm = m; mm < MAXDET; mm++) { pidx[mm] = 0; pok[mm] = 0; }
      break;
    }
    uint32_t pick = ((uint32_t)g) ^ 0xFFFFFFFFu;
    if (tid == 0) { pidx[m] = pick; pok[m] = 1; }
    // owner publishes the pick's box and deactivates it
#pragma unroll
    for (int j = 0; j < PC; j++) {
      if (((actmask >> j) & 1u) && key[j] == g) {
        pickbox[0] = bx[j][0]; pickbox[1] = bx[j][1];
        pickbox[2] = bx[j][2]; pickbox[3] = bx[j][3];
        actmask &= ~(1u << j);
      }
    }
    __syncthreads();
    const float a_r = pickbox[0], b_r = pickbox[1], c_r = pickbox[2], d_r = pickbox[3];
    const float area_r = (c_r - a_r) * (d_r - b_r);
#pragma unroll
    for (int j = 0; j < PC; j++) {
      if ((actmask >> j) & 1u) {
        float a = bx[j][0], bb = bx[j][1], c = bx[j][2], d = bx[j][3];
        float area_b = (c - a) * (d - bb);
        float ih = fmaxf(0.f, fminf(c_r, c) - fmaxf(a_r, a));
        float iw = fmaxf(0.f, fminf(d_r, d) - fmaxf(b_r, bb));
        float inter = ih * iw;
        float uni = area_r + area_b - inter;
        bool okk = (area_r > 0.f) && (area_b > 0.f) && (uni > 0.f);
        float iou = okk ? (inter / uni) : 0.f;
        if (iou > 0.5f) actmask &= ~(1u << j);
      }
    }
    __syncthreads();
  }
}

// ---------------- Kernel 3: gather outputs ----------------
__global__ void out_kernel(const float* __restrict__ box, const float* __restrict__ cls,
                           const uint32_t* __restrict__ pidx, const uint32_t* __restrict__ pok,
                           float* __restrict__ out, int N) {
  int r = blockIdx.x * blockDim.x + threadIdx.x;
  if (r >= BATCH * MAXDET) return;
  int b = r / MAXDET;
  float* boxes_out  = out;
  float* clsidx_out = out + BATCH * MAXDET * 4;
  float* cls_out    = out + BATCH * MAXDET * 4 + BATCH * MAXDET;

  uint32_t ok = pok[r];
  uint32_t idx = pidx[r];
  if (!ok) {
    boxes_out[r * 4 + 0] = 0.f; boxes_out[r * 4 + 1] = 0.f;
    boxes_out[r * 4 + 2] = 0.f; boxes_out[r * 4 + 3] = 0.f;
    clsidx_out[r] = 0.f;
    for (int j = 0; j < NCLS; j++) cls_out[r * NCLS + j] = 0.f;
    return;
  }
  const float4 f = *(const float4*)(box + ((size_t)b * N + idx) * 4);
  boxes_out[r * 4 + 0] = f.x;
  boxes_out[r * 4 + 1] = f.y;
  boxes_out[r * 4 + 2] = f.z - f.x;
  boxes_out[r * 4 + 3] = f.w - f.y;

  const float4* p = (const float4*)(cls + ((size_t)b * N + idx) * NCLS);
  float x[NCLS];
#pragma unroll
  for (int i = 0; i < NCLS / 4; i++) {
    float4 v = p[i];
    x[4 * i] = v.x; x[4 * i + 1] = v.y; x[4 * i + 2] = v.z; x[4 * i + 3] = v.w;
  }
  float m = x[0];
#pragma unroll
  for (int i = 1; i < NCLS; i++) m = fmaxf(m, x[i]);
  float e[NCLS];
#pragma unroll
  for (int i = 0; i < NCLS; i++) e[i] = expf(x[i] - m);
  float r8[8];
#pragma unroll
  for (int j = 0; j < 8; j++) r8[j] = 0.0f;
#pragma unroll
  for (int i = 0; i < NCLS / 8; i++)
#pragma unroll
    for (int j = 0; j < 8; j++) r8[j] += e[i * 8 + j];
  float s = ((r8[0] + r8[1]) + (r8[2] + r8[3])) + ((r8[4] + r8[5]) + (r8[6] + r8[7]));

  float best = -1.f; int bi = 0;
  for (int j = 0; j < NCLS; j++) {
    float pj = e[j] / s;            // division, matching reference
    cls_out[r * NCLS + j] = pj;
    if (pj > best) { best = pj; bi = j; }
  }
  clsidx_out[r] = (float)bi;
}

extern "C" void kernel_launch(void* const* d_in, const int* in_sizes, int n_in,
                              void* d_out, int out_size, void* d_ws, size_t ws_size,
                              hipStream_t stream) {
  (void)n_in; (void)out_size; (void)ws_size;
  const float* box = (const float*)d_in[0];
  const float* cls = (const float*)d_in[1];
  const int N = in_sizes[0] / (BATCH * 4);
  const int BN = BATCH * N;

  float* ws_scores = (float*)d_ws;                       // BATCH*N floats
  uint32_t* pidx = (uint32_t*)(ws_scores + (size_t)BN);  // BATCH*MAXDET
  uint32_t* pok  = pidx + BATCH * MAXDET;                // BATCH*MAXDET

  scores_kernel<<<(BN + 255) / 256, 256, 0, stream>>>(cls, ws_scores, BN);
  nms_kernel<<<BATCH, 1024, 0, stream>>>(box, ws_scores, pidx, pok, N);
  out_kernel<<<(BATCH * MAXDET + 255) / 256, 256, 0, stream>>>(box, cls, pidx, pok,
                                                               (float*)d_out, N);
}

// Round 2
// 624.403 us; speedup vs baseline: 2.5563x; 2.5563x over previous
//
#include <hip/hip_runtime.h>
#include <stdint.h>

#define BATCH 8
#define NCLS 80
#define MAXDET 100
#define CAP 2048
#define NBINS 10240          // keys 0..10036 (score 1.0) fit without clamping
#define CHUNKB 40            // 256 threads * 40 bins = 10240
#define BASEKEY (0x3D4CCCCDu >> 12)   // float bits of 0.05f >> 12

// ---------------- Kernel 0: zero per-call state ----------------
__global__ void zero_kernel(uint32_t* __restrict__ ghist, uint32_t* __restrict__ ctr,
                            uint32_t* __restrict__ Tb) {
  int i = blockIdx.x * blockDim.x + threadIdx.x;
  if (i < BATCH * NBINS) ghist[i] = 0;
  if (i < BATCH) { ctr[i] = 0; Tb[i] = NBINS; }
}

// ---------------- Kernel 1: scores = max softmax prob per row, + histogram ----------------
__global__ void scores_kernel(const float* __restrict__ cls,
                              float* __restrict__ scores,
                              uint32_t* __restrict__ ghist, int N, int BN) {
  int r = blockIdx.x * blockDim.x + threadIdx.x;
  if (r >= BN) return;
  const float4* p = (const float4*)(cls + (size_t)r * NCLS);
  float x[NCLS];
#pragma unroll
  for (int i = 0; i < NCLS / 4; i++) {
    float4 v = p[i];
    x[4 * i] = v.x; x[4 * i + 1] = v.y; x[4 * i + 2] = v.z; x[4 * i + 3] = v.w;
  }
  float m = x[0];
#pragma unroll
  for (int i = 1; i < NCLS; i++) m = fmaxf(m, x[i]);
  float r8[8];
#pragma unroll
  for (int j = 0; j < 8; j++) r8[j] = 0.0f;
#pragma unroll
  for (int i = 0; i < NCLS / 8; i++)
#pragma unroll
    for (int j = 0; j < 8; j++) r8[j] += expf(x[i * 8 + j] - m);
  float s = ((r8[0] + r8[1]) + (r8[2] + r8[3])) + ((r8[4] + r8[5]) + (r8[6] + r8[7]));
  float sc = 1.0f / s;
  scores[r] = sc;
  if (sc >= 0.05f) {
    int b = r / N;
    uint32_t key = (__float_as_uint(sc) >> 12) - BASEKEY;
    atomicAdd(&ghist[b * NBINS + key], 1u);
  }
}

// ---------------- Kernel 2: per-batch threshold bin (suffix count <= CAP) ----------------
__global__ __launch_bounds__(256)
void thresh_kernel(const uint32_t* __restrict__ ghist, uint32_t* __restrict__ Tb) {
  __shared__ uint32_t chs[256];
  const int b = blockIdx.x;
  const int tid = threadIdx.x;
  const uint32_t* h = ghist + b * NBINS;
  uint32_t csum = 0;
#pragma unroll
  for (int j = 0; j < CHUNKB; j++) csum += h[tid * CHUNKB + j];
  chs[tid] = csum;
  __syncthreads();
  for (int off = 1; off < 256; off <<= 1) {
    uint32_t v = chs[tid];
    uint32_t add = (tid + off < 256) ? chs[tid + off] : 0u;
    __syncthreads();
    chs[tid] = v + add;
    __syncthreads();
  }
  uint32_t St = chs[tid];
  uint32_t Sprev = (tid > 0) ? chs[tid - 1] : 0xFFFFFFFFu;
  if (St <= CAP && (tid == 0 || Sprev > CAP)) {
    int T = 0;
    if (tid != 0) {
      uint32_t cum = St;
      int lo = (tid - 1) * CHUNKB;
      T = lo;
      for (int bb = tid * CHUNKB - 1; bb >= lo; bb--) {
        uint32_t nb = cum + h[bb];
        if (nb > CAP) { T = bb + 1; break; }
        cum = nb;
        if (bb == lo) T = lo;
      }
    }
    Tb[b] = (uint32_t)T;
  }
}

// ---------------- Kernel 3: compact candidates >= threshold ----------------
__global__ void compact_kernel(const float* __restrict__ scores,
                               const uint32_t* __restrict__ Tb,
                               uint32_t* __restrict__ ctr,
                               uint32_t* __restrict__ csb, uint32_t* __restrict__ cidx,
                               int N, int BN) {
  int r = blockIdx.x * blockDim.x + threadIdx.x;
  if (r >= BN) return;
  float s = scores[r];
  if (s < 0.05f) return;
  int b = r / N;
  uint32_t key = (__float_as_uint(s) >> 12) - BASEKEY;
  if (key < Tb[b]) return;
  uint32_t slot = atomicAdd(&ctr[b], 1u);
  if (slot < CAP) {
    csb[b * CAP + slot] = __float_as_uint(s);
    cidx[b * CAP + slot] = (uint32_t)(r - b * N);
  }
}

// ---------------- Kernel 4: per-batch greedy NMS, all state in registers ----------------
__global__ __launch_bounds__(256, 1)
void nms_kernel(const float* __restrict__ box,
                const uint32_t* __restrict__ csb, const uint32_t* __restrict__ cidx,
                const uint32_t* __restrict__ ctr,
                uint32_t* __restrict__ pick_idx, uint32_t* __restrict__ pick_ok, int N) {
  __shared__ unsigned long long wavemax[4];
  __shared__ unsigned long long gkey_sh;
  __shared__ float pickbox[4];

  const int b = blockIdx.x;
  const int tid = threadIdx.x;
  uint32_t nc = ctr[b]; if (nc > CAP) nc = CAP;

  const int PC = CAP / 256;  // 8
  float bx[PC][4];
  unsigned long long key[PC];
  uint32_t actmask = 0;
#pragma unroll
  for (int j = 0; j < PC; j++) {
    int slot = tid + j * 256;
    key[j] = 0ULL;
    bx[j][0] = bx[j][1] = bx[j][2] = bx[j][3] = 0.f;
    if (slot < (int)nc) {
      uint32_t sb = csb[b * CAP + slot];
      uint32_t idx = cidx[b * CAP + slot];
      const float4 f = *(const float4*)(box + ((size_t)b * N + idx) * 4);
      bx[j][0] = f.x; bx[j][1] = f.y; bx[j][2] = f.z - f.x; bx[j][3] = f.w - f.y;
      key[j] = ((unsigned long long)sb << 32) | (unsigned long long)(idx ^ 0xFFFFFFFFu);
      actmask |= (1u << j);
    }
  }

  uint32_t* pidx = pick_idx + b * MAXDET;
  uint32_t* pok  = pick_ok  + b * MAXDET;
  const int wid = tid >> 6, lane = tid & 63;

  for (int m = 0; m < MAXDET; m++) {
    unsigned long long k = 0ULL;
#pragma unroll
    for (int j = 0; j < PC; j++)
      if ((actmask >> j) & 1u) { if (key[j] > k) k = key[j]; }
#pragma unroll
    for (int off = 32; off > 0; off >>= 1) {
      unsigned long long o = __shfl_xor(k, off);
      if (o > k) k = o;
    }
    if (lane == 0) wavemax[wid] = k;
    __syncthreads();
    if (tid == 0) {
      unsigned long long g = wavemax[0];
      if (wavemax[1] > g) g = wavemax[1];
      if (wavemax[2] > g) g = wavemax[2];
      if (wavemax[3] > g) g = wavemax[3];
      gkey_sh = g;
    }
    __syncthreads();
    unsigned long long g = gkey_sh;
    if (g == 0ULL) {
      if (tid == 0) for (int mm = m; mm < MAXDET; mm++) { pidx[mm] = 0; pok[mm] = 0; }
      break;
    }
    uint32_t pick = ((uint32_t)g) ^ 0xFFFFFFFFu;
    if (tid == 0) { pidx[m] = pick; pok[m] = 1; }
#pragma unroll
    for (int j = 0; j < PC; j++) {
      if (((actmask >> j) & 1u) && key[j] == g) {
        pickbox[0] = bx[j][0]; pickbox[1] = bx[j][1];
        pickbox[2] = bx[j][2]; pickbox[3] = bx[j][3];
        actmask &= ~(1u << j);
      }
    }
    __syncthreads();
    const float a_r = pickbox[0], b_r = pickbox[1], c_r = pickbox[2], d_r = pickbox[3];
    const float area_r = (c_r - a_r) * (d_r - b_r);
#pragma unroll
    for (int j = 0; j < PC; j++) {
      if ((actmask >> j) & 1u) {
        float a = bx[j][0], bb = bx[j][1], c = bx[j][2], d = bx[j][3];
        float area_b = (c - a) * (d - bb);
        float ih = fmaxf(0.f, fminf(c_r, c) - fmaxf(a_r, a));
        float iw = fmaxf(0.f, fminf(d_r, d) - fmaxf(b_r, bb));
        float inter = ih * iw;
        float uni = area_r + area_b - inter;
        bool okk = (area_r > 0.f) && (area_b > 0.f) && (uni > 0.f);
        float iou = okk ? (inter / uni) : 0.f;
        if (iou > 0.5f) actmask &= ~(1u << j);
      }
    }
    __syncthreads();
  }
}

// ---------------- Kernel 5: gather outputs ----------------
__global__ void out_kernel(const float* __restrict__ box, const float* __restrict__ cls,
                           const uint32_t* __restrict__ pidx, const uint32_t* __restrict__ pok,
                           float* __restrict__ out, int N) {
  int r = blockIdx.x * blockDim.x + threadIdx.x;
  if (r >= BATCH * MAXDET) return;
  int b = r / MAXDET;
  float* boxes_out  = out;
  float* clsidx_out = out + BATCH * MAXDET * 4;
  float* cls_out    = out + BATCH * MAXDET * 4 + BATCH * MAXDET;

  uint32_t ok = pok[r];
  uint32_t idx = pidx[r];
  if (!ok) {
    boxes_out[r * 4 + 0] = 0.f; boxes_out[r * 4 + 1] = 0.f;
    boxes_out[r * 4 + 2] = 0.f; boxes_out[r * 4 + 3] = 0.f;
    clsidx_out[r] = 0.f;
    for (int j = 0; j < NCLS; j++) cls_out[r * NCLS + j] = 0.f;
    return;
  }
  const float4 f = *(const float4*)(box + ((size_t)b * N + idx) * 4);
  boxes_out[r * 4 + 0] = f.x;
  boxes_out[r * 4 + 1] = f.y;
  boxes_out[r * 4 + 2] = f.z - f.x;
  boxes_out[r * 4 + 3] = f.w - f.y;

  const float4* p = (const float4*)(cls + ((size_t)b * N + idx) * NCLS);
  float x[NCLS];
#pragma unroll
  for (int i = 0; i < NCLS / 4; i++) {
    float4 v = p[i];
    x[4 * i] = v.x; x[4 * i + 1] = v.y; x[4 * i + 2] = v.z; x[4 * i + 3] = v.w;
  }
  float m = x[0];
#pragma unroll
  for (int i = 1; i < NCLS; i++) m = fmaxf(m, x[i]);
  float e[NCLS];
#pragma unroll
  for (int i = 0; i < NCLS; i++) e[i] = expf(x[i] - m);
  float r8[8];
#pragma unroll
  for (int j = 0; j < 8; j++) r8[j] = 0.0f;
#pragma unroll
  for (int i = 0; i < NCLS / 8; i++)
#pragma unroll
    for (int j = 0; j < 8; j++) r8[j] += e[i * 8 + j];
  float s = ((r8[0] + r8[1]) + (r8[2] + r8[3])) + ((r8[4] + r8[5]) + (r8[6] + r8[7]));

  float best = -1.f; int bi = 0;
  for (int j = 0; j < NCLS; j++) {
    float pj = e[j] / s;
    cls_out[r * NCLS + j] = pj;
    if (pj > best) { best = pj; bi = j; }
  }
  clsidx_out[r] = (float)bi;
}

extern "C" void kernel_launch(void* const* d_in, const int* in_sizes, int n_in,
                              void* d_out, int out_size, void* d_ws, size_t ws_size,
                              hipStream_t stream) {
  (void)n_in; (void)out_size; (void)ws_size;
  const float* box = (const float*)d_in[0];
  const float* cls = (const float*)d_in[1];
  const int N = in_sizes[0] / (BATCH * 4);
  const int BN = BATCH * N;

  float*    ws_scores = (float*)d_ws;                          // BN floats
  uint32_t* ghist = (uint32_t*)(ws_scores + (size_t)BN);       // BATCH*NBINS
  uint32_t* ctr   = ghist + BATCH * NBINS;                     // BATCH
  uint32_t* Tb    = ctr + BATCH;                               // BATCH
  uint32_t* csb   = Tb + BATCH;                                // BATCH*CAP
  uint32_t* cidx  = csb + BATCH * CAP;                         // BATCH*CAP
  uint32_t* pidx  = cidx + BATCH * CAP;                        // BATCH*MAXDET
  uint32_t* pok   = pidx + BATCH * MAXDET;                     // BATCH*MAXDET

  zero_kernel<<<(BATCH * NBINS + 255) / 256, 256, 0, stream>>>(ghist, ctr, Tb);
  scores_kernel<<<(BN + 255) / 256, 256, 0, stream>>>(cls, ws_scores, ghist, N, BN);
  thresh_kernel<<<BATCH, 256, 0, stream>>>(ghist, Tb);
  compact_kernel<<<(BN + 255) / 256, 256, 0, stream>>>(ws_scores, Tb, ctr, csb, cidx, N, BN);
  nms_kernel<<<BATCH, 256, 0, stream>>>(box, csb, cidx, ctr, pidx, pok, N);
  out_kernel<<<(BATCH * MAXDET + 255) / 256, 256, 0, stream>>>(box, cls, pidx, pok,
                                                               (float*)d_out, N);
}

// Round 3
// 310.466 us; speedup vs baseline: 5.1411x; 2.0112x over previous
//
#include <hip/hip_runtime.h>
#include <stdint.h>

#define BATCH 8
#define NCLS 80
#define MAXDET 100
#define CAP 2048
#define NBINS 10240          // keys 0..10036 (score 1.0) fit without clamping
#define CHUNKB 40            // 256 threads * 40 bins = 10240
#define BASEKEY (0x3D4CCCCDu >> 12)   // float bits of 0.05f >> 12

// ---------------- Kernel 0: zero per-call state ----------------
__global__ void zero_kernel(uint32_t* __restrict__ ghist, uint32_t* __restrict__ ctr,
                            uint32_t* __restrict__ Tb) {
  int i = blockIdx.x * blockDim.x + threadIdx.x;
  if (i < BATCH * NBINS) ghist[i] = 0;
  if (i < BATCH) { ctr[i] = 0; Tb[i] = NBINS; }
}

// ---------------- Kernel 1: scores = max softmax prob per row, + histogram ----------------
__global__ void scores_kernel(const float* __restrict__ cls,
                              float* __restrict__ scores,
                              uint32_t* __restrict__ ghist, int N, int BN) {
  int r = blockIdx.x * blockDim.x + threadIdx.x;
  if (r >= BN) return;
  const float4* p = (const float4*)(cls + (size_t)r * NCLS);
  float x[NCLS];
#pragma unroll
  for (int i = 0; i < NCLS / 4; i++) {
    float4 v = p[i];
    x[4 * i] = v.x; x[4 * i + 1] = v.y; x[4 * i + 2] = v.z; x[4 * i + 3] = v.w;
  }
  float m = x[0];
#pragma unroll
  for (int i = 1; i < NCLS; i++) m = fmaxf(m, x[i]);
  float r8[8];
#pragma unroll
  for (int j = 0; j < 8; j++) r8[j] = 0.0f;
#pragma unroll
  for (int i = 0; i < NCLS / 8; i++)
#pragma unroll
    for (int j = 0; j < 8; j++) r8[j] += expf(x[i * 8 + j] - m);
  float s = ((r8[0] + r8[1]) + (r8[2] + r8[3])) + ((r8[4] + r8[5]) + (r8[6] + r8[7]));
  float sc = 1.0f / s;
  scores[r] = sc;
  if (sc >= 0.05f) {
    int b = r / N;
    uint32_t key = (__float_as_uint(sc) >> 12) - BASEKEY;
    atomicAdd(&ghist[b * NBINS + key], 1u);
  }
}

// ---------------- Kernel 2: per-batch threshold bin (suffix count <= CAP) ----------------
__global__ __launch_bounds__(256)
void thresh_kernel(const uint32_t* __restrict__ ghist, uint32_t* __restrict__ Tb) {
  __shared__ uint32_t chs[256];
  const int b = blockIdx.x;
  const int tid = threadIdx.x;
  const uint32_t* h = ghist + b * NBINS;
  uint32_t csum = 0;
#pragma unroll
  for (int j = 0; j < CHUNKB; j++) csum += h[tid * CHUNKB + j];
  chs[tid] = csum;
  __syncthreads();
  for (int off = 1; off < 256; off <<= 1) {
    uint32_t v = chs[tid];
    uint32_t add = (tid + off < 256) ? chs[tid + off] : 0u;
    __syncthreads();
    chs[tid] = v + add;
    __syncthreads();
  }
  uint32_t St = chs[tid];
  uint32_t Sprev = (tid > 0) ? chs[tid - 1] : 0xFFFFFFFFu;
  if (St <= CAP && (tid == 0 || Sprev > CAP)) {
    int T = 0;
    if (tid != 0) {
      uint32_t cum = St;
      int lo = (tid - 1) * CHUNKB;
      T = lo;
      for (int bb = tid * CHUNKB - 1; bb >= lo; bb--) {
        uint32_t nb = cum + h[bb];
        if (nb > CAP) { T = bb + 1; break; }
        cum = nb;
        if (bb == lo) T = lo;
      }
    }
    Tb[b] = (uint32_t)T;
  }
}

// ---------------- Kernel 3: hierarchical compact (1 atomic per block) ----------------
__global__ __launch_bounds__(1024)
void compact_kernel(const float* __restrict__ scores,
                    const uint32_t* __restrict__ Tb,
                    uint32_t* __restrict__ ctr,
                    uint32_t* __restrict__ csb, uint32_t* __restrict__ cidx,
                    int N) {
  __shared__ uint32_t wbase[16];
  __shared__ uint32_t blkbase;
  const int b = blockIdx.y;
  const int i = blockIdx.x * 1024 + threadIdx.x;
  const int lane = threadIdx.x & 63, wid = threadIdx.x >> 6;

  bool q = false;
  float s = 0.f;
  if (i < N) {
    s = scores[(size_t)b * N + i];
    if (s >= 0.05f) {
      uint32_t key = (__float_as_uint(s) >> 12) - BASEKEY;
      q = key >= Tb[b];
    }
  }
  unsigned long long mask = __ballot(q);
  uint32_t wcnt = (uint32_t)__popcll(mask);
  uint32_t lpre = (uint32_t)__popcll(mask & ((1ULL << lane) - 1ULL));
  if (lane == 0) wbase[wid] = wcnt;
  __syncthreads();
  if (threadIdx.x == 0) {
    uint32_t tot = 0;
#pragma unroll
    for (int w = 0; w < 16; w++) { uint32_t c = wbase[w]; wbase[w] = tot; tot += c; }
    blkbase = tot ? atomicAdd(&ctr[b], tot) : 0u;
  }
  __syncthreads();
  if (q) {
    uint32_t slot = blkbase + wbase[wid] + lpre;
    if (slot < CAP) {
      csb[b * CAP + slot] = __float_as_uint(s);
      cidx[b * CAP + slot] = (uint32_t)i;
    }
  }
}

// ---------------- Kernel 4: per-batch greedy NMS, all state in registers ----------------
__global__ __launch_bounds__(256, 1)
void nms_kernel(const float* __restrict__ box,
                const uint32_t* __restrict__ csb, const uint32_t* __restrict__ cidx,
                const uint32_t* __restrict__ ctr,
                uint32_t* __restrict__ pick_idx, uint32_t* __restrict__ pick_ok, int N) {
  __shared__ unsigned long long wavemax[4];
  __shared__ unsigned long long gkey_sh;
  __shared__ float pickbox[4];

  const int b = blockIdx.x;
  const int tid = threadIdx.x;
  uint32_t nc = ctr[b]; if (nc > CAP) nc = CAP;

  const int PC = CAP / 256;  // 8
  float bx[PC][4];
  unsigned long long key[PC];
  uint32_t actmask = 0;
#pragma unroll
  for (int j = 0; j < PC; j++) {
    int slot = tid + j * 256;
    key[j] = 0ULL;
    bx[j][0] = bx[j][1] = bx[j][2] = bx[j][3] = 0.f;
    if (slot < (int)nc) {
      uint32_t sb = csb[b * CAP + slot];
      uint32_t idx = cidx[b * CAP + slot];
      const float4 f = *(const float4*)(box + ((size_t)b * N + idx) * 4);
      bx[j][0] = f.x; bx[j][1] = f.y; bx[j][2] = f.z - f.x; bx[j][3] = f.w - f.y;
      key[j] = ((unsigned long long)sb << 32) | (unsigned long long)(idx ^ 0xFFFFFFFFu);
      actmask |= (1u << j);
    }
  }

  uint32_t* pidx = pick_idx + b * MAXDET;
  uint32_t* pok  = pick_ok  + b * MAXDET;
  const int wid = tid >> 6, lane = tid & 63;

  for (int m = 0; m < MAXDET; m++) {
    unsigned long long k = 0ULL;
#pragma unroll
    for (int j = 0; j < PC; j++)
      if ((actmask >> j) & 1u) { if (key[j] > k) k = key[j]; }
#pragma unroll
    for (int off = 32; off > 0; off >>= 1) {
      unsigned long long o = __shfl_xor(k, off);
      if (o > k) k = o;
    }
    if (lane == 0) wavemax[wid] = k;
    __syncthreads();
    if (tid == 0) {
      unsigned long long g = wavemax[0];
      if (wavemax[1] > g) g = wavemax[1];
      if (wavemax[2] > g) g = wavemax[2];
      if (wavemax[3] > g) g = wavemax[3];
      gkey_sh = g;
    }
    __syncthreads();
    unsigned long long g = gkey_sh;
    if (g == 0ULL) {
      if (tid == 0) for (int mm = m; mm < MAXDET; mm++) { pidx[mm] = 0; pok[mm] = 0; }
      break;
    }
    uint32_t pick = ((uint32_t)g) ^ 0xFFFFFFFFu;
    if (tid == 0) { pidx[m] = pick; pok[m] = 1; }
#pragma unroll
    for (int j = 0; j < PC; j++) {
      if (((actmask >> j) & 1u) && key[j] == g) {
        pickbox[0] = bx[j][0]; pickbox[1] = bx[j][1];
        pickbox[2] = bx[j][2]; pickbox[3] = bx[j][3];
        actmask &= ~(1u << j);
      }
    }
    __syncthreads();
    const float a_r = pickbox[0], b_r = pickbox[1], c_r = pickbox[2], d_r = pickbox[3];
    const float area_r = (c_r - a_r) * (d_r - b_r);
#pragma unroll
    for (int j = 0; j < PC; j++) {
      if ((actmask >> j) & 1u) {
        float a = bx[j][0], bb = bx[j][1], c = bx[j][2], d = bx[j][3];
        float area_b = (c - a) * (d - bb);
        float ih = fmaxf(0.f, fminf(c_r, c) - fmaxf(a_r, a));
        float iw = fmaxf(0.f, fminf(d_r, d) - fmaxf(b_r, bb));
        float inter = ih * iw;
        float uni = area_r + area_b - inter;
        bool okk = (area_r > 0.f) && (area_b > 0.f) && (uni > 0.f);
        float iou = okk ? (inter / uni) : 0.f;
        if (iou > 0.5f) actmask &= ~(1u << j);
      }
    }
    __syncthreads();
  }
}

// ---------------- Kernel 5: gather outputs ----------------
__global__ void out_kernel(const float* __restrict__ box, const float* __restrict__ cls,
                           const uint32_t* __restrict__ pidx, const uint32_t* __restrict__ pok,
                           float* __restrict__ out, int N) {
  int r = blockIdx.x * blockDim.x + threadIdx.x;
  if (r >= BATCH * MAXDET) return;
  int b = r / MAXDET;
  float* boxes_out  = out;
  float* clsidx_out = out + BATCH * MAXDET * 4;
  float* cls_out    = out + BATCH * MAXDET * 4 + BATCH * MAXDET;

  uint32_t ok = pok[r];
  uint32_t idx = pidx[r];
  if (!ok) {
    boxes_out[r * 4 + 0] = 0.f; boxes_out[r * 4 + 1] = 0.f;
    boxes_out[r * 4 + 2] = 0.f; boxes_out[r * 4 + 3] = 0.f;
    clsidx_out[r] = 0.f;
    for (int j = 0; j < NCLS; j++) cls_out[r * NCLS + j] = 0.f;
    return;
  }
  const float4 f = *(const float4*)(box + ((size_t)b * N + idx) * 4);
  boxes_out[r * 4 + 0] = f.x;
  boxes_out[r * 4 + 1] = f.y;
  boxes_out[r * 4 + 2] = f.z - f.x;
  boxes_out[r * 4 + 3] = f.w - f.y;

  const float4* p = (const float4*)(cls + ((size_t)b * N + idx) * NCLS);
  float x[NCLS];
#pragma unroll
  for (int i = 0; i < NCLS / 4; i++) {
    float4 v = p[i];
    x[4 * i] = v.x; x[4 * i + 1] = v.y; x[4 * i + 2] = v.z; x[4 * i + 3] = v.w;
  }
  float m = x[0];
#pragma unroll
  for (int i = 1; i < NCLS; i++) m = fmaxf(m, x[i]);
  float e[NCLS];
#pragma unroll
  for (int i = 0; i < NCLS; i++) e[i] = expf(x[i] - m);
  float r8[8];
#pragma unroll
  for (int j = 0; j < 8; j++) r8[j] = 0.0f;
#pragma unroll
  for (int i = 0; i < NCLS / 8; i++)
#pragma unroll
    for (int j = 0; j < 8; j++) r8[j] += e[i * 8 + j];
  float s = ((r8[0] + r8[1]) + (r8[2] + r8[3])) + ((r8[4] + r8[5]) + (r8[6] + r8[7]));

  float best = -1.f; int bi = 0;
  for (int j = 0; j < NCLS; j++) {
    float pj = e[j] / s;
    cls_out[r * NCLS + j] = pj;
    if (pj > best) { best = pj; bi = j; }
  }
  clsidx_out[r] = (float)bi;
}

extern "C" void kernel_launch(void* const* d_in, const int* in_sizes, int n_in,
                              void* d_out, int out_size, void* d_ws, size_t ws_size,
                              hipStream_t stream) {
  (void)n_in; (void)out_size; (void)ws_size;
  const float* box = (const float*)d_in[0];
  const float* cls = (const float*)d_in[1];
  const int N = in_sizes[0] / (BATCH * 4);
  const int BN = BATCH * N;

  float*    ws_scores = (float*)d_ws;                          // BN floats
  uint32_t* ghist = (uint32_t*)(ws_scores + (size_t)BN);       // BATCH*NBINS
  uint32_t* ctr   = ghist + BATCH * NBINS;                     // BATCH
  uint32_t* Tb    = ctr + BATCH;                               // BATCH
  uint32_t* csb   = Tb + BATCH;                                // BATCH*CAP
  uint32_t* cidx  = csb + BATCH * CAP;                         // BATCH*CAP
  uint32_t* pidx  = cidx + BATCH * CAP;                        // BATCH*MAXDET
  uint32_t* pok   = pidx + BATCH * MAXDET;                     // BATCH*MAXDET

  zero_kernel<<<(BATCH * NBINS + 255) / 256, 256, 0, stream>>>(ghist, ctr, Tb);
  scores_kernel<<<(BN + 255) / 256, 256, 0, stream>>>(cls, ws_scores, ghist, N, BN);
  thresh_kernel<<<BATCH, 256, 0, stream>>>(ghist, Tb);
  dim3 cgrid((N + 1023) / 1024, BATCH);
  compact_kernel<<<cgrid, 1024, 0, stream>>>(ws_scores, Tb, ctr, csb, cidx, N);
  nms_kernel<<<BATCH, 256, 0, stream>>>(box, csb, cidx, ctr, pidx, pok, N);
  out_kernel<<<(BATCH * MAXDET + 255) / 256, 256, 0, stream>>>(box, cls, pidx, pok,
                                                               (float*)d_out, N);
}

// Round 4
// 288.060 us; speedup vs baseline: 5.5410x; 1.0778x over previous
//
#include <hip/hip_runtime.h>
#include <stdint.h>

#define BATCH 8
#define NCLS 80
#define MAXDET 100
#define CAP 1024
#define NBINS 10240          // keys 0..10036 (score 1.0) fit without clamping
#define CHUNKB 40            // 256 threads * 40 bins = 10240
#define BASEKEY (0x3D4CCCCDu >> 12)   // float bits of 0.05f >> 12

// ---------------- Kernel 0: zero per-call state ----------------
__global__ void zero_kernel(uint32_t* __restrict__ ghist, uint32_t* __restrict__ ctr,
                            uint32_t* __restrict__ Tb) {
  int i = blockIdx.x * blockDim.x + threadIdx.x;
  if (i < BATCH * NBINS) ghist[i] = 0;
  if (i < BATCH) { ctr[i] = 0; Tb[i] = NBINS; }
}

// ---------------- Kernel 1: scores = max softmax prob per row, + histogram ----------------
__global__ void scores_kernel(const float* __restrict__ cls,
                              float* __restrict__ scores,
                              uint32_t* __restrict__ ghist, int N, int BN) {
  int r = blockIdx.x * blockDim.x + threadIdx.x;
  if (r >= BN) return;
  const float4* p = (const float4*)(cls + (size_t)r * NCLS);
  float x[NCLS];
#pragma unroll
  for (int i = 0; i < NCLS / 4; i++) {
    float4 v = p[i];
    x[4 * i] = v.x; x[4 * i + 1] = v.y; x[4 * i + 2] = v.z; x[4 * i + 3] = v.w;
  }
  float m = x[0];
#pragma unroll
  for (int i = 1; i < NCLS; i++) m = fmaxf(m, x[i]);
  float r8[8];
#pragma unroll
  for (int j = 0; j < 8; j++) r8[j] = 0.0f;
#pragma unroll
  for (int i = 0; i < NCLS / 8; i++)
#pragma unroll
    for (int j = 0; j < 8; j++) r8[j] += expf(x[i * 8 + j] - m);
  float s = ((r8[0] + r8[1]) + (r8[2] + r8[3])) + ((r8[4] + r8[5]) + (r8[6] + r8[7]));
  float sc = 1.0f / s;
  scores[r] = sc;
  if (sc >= 0.05f) {
    int b = r / N;
    uint32_t key = (__float_as_uint(sc) >> 12) - BASEKEY;
    atomicAdd(&ghist[b * NBINS + key], 1u);
  }
}

// ---------------- Kernel 2: per-batch threshold bin (suffix count <= CAP) ----------------
__global__ __launch_bounds__(256)
void thresh_kernel(const uint32_t* __restrict__ ghist, uint32_t* __restrict__ Tb) {
  __shared__ uint32_t chs[256];
  const int b = blockIdx.x;
  const int tid = threadIdx.x;
  const uint32_t* h = ghist + b * NBINS;
  uint32_t csum = 0;
#pragma unroll
  for (int j = 0; j < CHUNKB; j++) csum += h[tid * CHUNKB + j];
  chs[tid] = csum;
  __syncthreads();
  for (int off = 1; off < 256; off <<= 1) {
    uint32_t v = chs[tid];
    uint32_t add = (tid + off < 256) ? chs[tid + off] : 0u;
    __syncthreads();
    chs[tid] = v + add;
    __syncthreads();
  }
  uint32_t St = chs[tid];
  uint32_t Sprev = (tid > 0) ? chs[tid - 1] : 0xFFFFFFFFu;
  if (St <= CAP && (tid == 0 || Sprev > CAP)) {
    int T = 0;
    if (tid != 0) {
      uint32_t cum = St;
      int lo = (tid - 1) * CHUNKB;
      T = lo;
      for (int bb = tid * CHUNKB - 1; bb >= lo; bb--) {
        uint32_t nb = cum + h[bb];
        if (nb > CAP) { T = bb + 1; break; }
        cum = nb;
        if (bb == lo) T = lo;
      }
    }
    Tb[b] = (uint32_t)T;
  }
}

// ---------------- Kernel 3: hierarchical compact (1 atomic per block) ----------------
__global__ __launch_bounds__(1024)
void compact_kernel(const float* __restrict__ scores,
                    const uint32_t* __restrict__ Tb,
                    uint32_t* __restrict__ ctr,
                    uint32_t* __restrict__ csb, uint32_t* __restrict__ cidx,
                    int N) {
  __shared__ uint32_t wbase[16];
  __shared__ uint32_t blkbase;
  const int b = blockIdx.y;
  const int i = blockIdx.x * 1024 + threadIdx.x;
  const int lane = threadIdx.x & 63, wid = threadIdx.x >> 6;

  bool q = false;
  float s = 0.f;
  if (i < N) {
    s = scores[(size_t)b * N + i];
    if (s >= 0.05f) {
      uint32_t key = (__float_as_uint(s) >> 12) - BASEKEY;
      q = key >= Tb[b];
    }
  }
  unsigned long long mask = __ballot(q);
  uint32_t wcnt = (uint32_t)__popcll(mask);
  uint32_t lpre = (uint32_t)__popcll(mask & ((1ULL << lane) - 1ULL));
  if (lane == 0) wbase[wid] = wcnt;
  __syncthreads();
  if (threadIdx.x == 0) {
    uint32_t tot = 0;
#pragma unroll
    for (int w = 0; w < 16; w++) { uint32_t c = wbase[w]; wbase[w] = tot; tot += c; }
    blkbase = tot ? atomicAdd(&ctr[b], tot) : 0u;
  }
  __syncthreads();
  if (q) {
    uint32_t slot = blkbase + wbase[wid] + lpre;
    if (slot < CAP) {
      csb[b * CAP + slot] = __float_as_uint(s);
      cidx[b * CAP + slot] = (uint32_t)i;
    }
  }
}

// ---------------- Kernel 4: sort + ordered-walk greedy NMS ----------------
// Sort candidates by (score_bits, ~idx) desc (bitonic, LDS), then greedy NMS
// = walk sorted order picking first-active; single-wave walk, no barriers.
__global__ __launch_bounds__(256, 1)
void nms_kernel(const float* __restrict__ box,
                const uint32_t* __restrict__ csb, const uint32_t* __restrict__ cidx,
                const uint32_t* __restrict__ ctr,
                uint32_t* __restrict__ pick_idx, uint32_t* __restrict__ pick_ok, int N) {
  __shared__ unsigned long long sk[CAP];
  __shared__ float sbox[CAP][4];
  __shared__ uint32_t sidx[CAP];

  const int b = blockIdx.x;
  const int tid = threadIdx.x;
  uint32_t nc = ctr[b]; if (nc > CAP) nc = CAP;

  // load keys (0 = empty; real keys nonzero since score bits >= 0.05f bits)
#pragma unroll
  for (int q = 0; q < CAP / 256; q++) {
    int s = tid + q * 256;
    unsigned long long k = 0ULL;
    if (s < (int)nc)
      k = ((unsigned long long)csb[b * CAP + s] << 32) |
          (unsigned long long)(cidx[b * CAP + s] ^ 0xFFFFFFFFu);
    sk[s] = k;
  }
  __syncthreads();

  // bitonic sort, descending
  for (int k = 2; k <= CAP; k <<= 1) {
    for (int j = k >> 1; j > 0; j >>= 1) {
#pragma unroll
      for (int q = 0; q < CAP / 256; q++) {
        int i = tid + q * 256;
        int ixj = i ^ j;
        if (ixj > i) {
          unsigned long long a = sk[i], c = sk[ixj];
          if (((i & k) == 0) ? (a < c) : (a > c)) { sk[i] = c; sk[ixj] = a; }
        }
      }
      __syncthreads();
    }
  }

  // gather boxes of sorted candidates into LDS (xywh corner-interp form)
#pragma unroll
  for (int q = 0; q < CAP / 256; q++) {
    int s = tid + q * 256;
    unsigned long long k = sk[s];
    uint32_t idx = (uint32_t)k ^ 0xFFFFFFFFu;
    sidx[s] = idx;
    if (k != 0ULL) {
      const float4 f = *(const float4*)(box + ((size_t)b * N + idx) * 4);
      sbox[s][0] = f.x; sbox[s][1] = f.y; sbox[s][2] = f.z - f.x; sbox[s][3] = f.w - f.y;
    } else {
      sbox[s][0] = 0.f; sbox[s][1] = 0.f; sbox[s][2] = 0.f; sbox[s][3] = 0.f;
    }
  }
  __syncthreads();
  if (tid >= 64) return;   // walk is wave0-only; no barriers below

  const int lane = tid;
  const int SPL = CAP / 64;  // 16 slots per lane, contiguous
  float bxj[SPL][4];
  uint32_t amask = 0;
#pragma unroll
  for (int j = 0; j < SPL; j++) {
    int s = lane * SPL + j;
    bxj[j][0] = sbox[s][0]; bxj[j][1] = sbox[s][1];
    bxj[j][2] = sbox[s][2]; bxj[j][3] = sbox[s][3];
    if (s < (int)nc) amask |= (1u << j);
  }

  uint32_t* pidx = pick_idx + b * MAXDET;
  uint32_t* pok  = pick_ok  + b * MAXDET;

  for (int m = 0; m < MAXDET; m++) {
    unsigned long long ball = __ballot(amask != 0u);
    if (ball == 0ULL) {
      if (lane == 0)
        for (int mm = m; mm < MAXDET; mm++) { pidx[mm] = 0; pok[mm] = 0; }
      break;
    }
    int L = (int)(__ffsll(ball) - 1);
    int fj = __ffs(amask) - 1;        // valid where amask != 0 (incl. lane L)
    int jsel = __shfl(fj, L);
    int p = L * SPL + jsel;
    if (lane == L) amask &= ~(1u << jsel);
    if (lane == 0) { pidx[m] = sidx[p]; pok[m] = 1; }
    const float a_r = sbox[p][0], b_r = sbox[p][1], c_r = sbox[p][2], d_r = sbox[p][3];
    const float area_r = (c_r - a_r) * (d_r - b_r);
#pragma unroll
    for (int j = 0; j < SPL; j++) {
      if ((amask >> j) & 1u) {
        float a = bxj[j][0], bb = bxj[j][1], c = bxj[j][2], d = bxj[j][3];
        float area_b = (c - a) * (d - bb);
        float ih = fmaxf(0.f, fminf(c_r, c) - fmaxf(a_r, a));
        float iw = fmaxf(0.f, fminf(d_r, d) - fmaxf(b_r, bb));
        float inter = ih * iw;
        float uni = area_r + area_b - inter;
        bool okk = (area_r > 0.f) && (area_b > 0.f) && (uni > 0.f);
        float iou = okk ? (inter / uni) : 0.f;
        if (iou > 0.5f) amask &= ~(1u << j);
      }
    }
  }
}

// ---------------- Kernel 5: gather outputs ----------------
__global__ void out_kernel(const float* __restrict__ box, const float* __restrict__ cls,
                           const uint32_t* __restrict__ pidx, const uint32_t* __restrict__ pok,
                           float* __restrict__ out, int N) {
  int r = blockIdx.x * blockDim.x + threadIdx.x;
  if (r >= BATCH * MAXDET) return;
  int b = r / MAXDET;
  float* boxes_out  = out;
  float* clsidx_out = out + BATCH * MAXDET * 4;
  float* cls_out    = out + BATCH * MAXDET * 4 + BATCH * MAXDET;

  uint32_t ok = pok[r];
  uint32_t idx = pidx[r];
  if (!ok) {
    boxes_out[r * 4 + 0] = 0.f; boxes_out[r * 4 + 1] = 0.f;
    boxes_out[r * 4 + 2] = 0.f; boxes_out[r * 4 + 3] = 0.f;
    clsidx_out[r] = 0.f;
    for (int j = 0; j < NCLS; j++) cls_out[r * NCLS + j] = 0.f;
    return;
  }
  const float4 f = *(const float4*)(box + ((size_t)b * N + idx) * 4);
  boxes_out[r * 4 + 0] = f.x;
  boxes_out[r * 4 + 1] = f.y;
  boxes_out[r * 4 + 2] = f.z - f.x;
  boxes_out[r * 4 + 3] = f.w - f.y;

  const float4* p = (const float4*)(cls + ((size_t)b * N + idx) * NCLS);
  float x[NCLS];
#pragma unroll
  for (int i = 0; i < NCLS / 4; i++) {
    float4 v = p[i];
    x[4 * i] = v.x; x[4 * i + 1] = v.y; x[4 * i + 2] = v.z; x[4 * i + 3] = v.w;
  }
  float m = x[0];
#pragma unroll
  for (int i = 1; i < NCLS; i++) m = fmaxf(m, x[i]);
  float e[NCLS];
#pragma unroll
  for (int i = 0; i < NCLS; i++) e[i] = expf(x[i] - m);
  float r8[8];
#pragma unroll
  for (int j = 0; j < 8; j++) r8[j] = 0.0f;
#pragma unroll
  for (int i = 0; i < NCLS / 8; i++)
#pragma unroll
    for (int j = 0; j < 8; j++) r8[j] += e[i * 8 + j];
  float s = ((r8[0] + r8[1]) + (r8[2] + r8[3])) + ((r8[4] + r8[5]) + (r8[6] + r8[7]));

  float best = -1.f; int bi = 0;
  for (int j = 0; j < NCLS; j++) {
    float pj = e[j] / s;
    cls_out[r * NCLS + j] = pj;
    if (pj > best) { best = pj; bi = j; }
  }
  clsidx_out[r] = (float)bi;
}

extern "C" void kernel_launch(void* const* d_in, const int* in_sizes, int n_in,
                              void* d_out, int out_size, void* d_ws, size_t ws_size,
                              hipStream_t stream) {
  (void)n_in; (void)out_size; (void)ws_size;
  const float* box = (const float*)d_in[0];
  const float* cls = (const float*)d_in[1];
  const int N = in_sizes[0] / (BATCH * 4);
  const int BN = BATCH * N;

  float*    ws_scores = (float*)d_ws;                          // BN floats
  uint32_t* ghist = (uint32_t*)(ws_scores + (size_t)BN);       // BATCH*NBINS
  uint32_t* ctr   = ghist + BATCH * NBINS;                     // BATCH
  uint32_t* Tb    = ctr + BATCH;                               // BATCH
  uint32_t* csb   = Tb + BATCH;                                // BATCH*CAP
  uint32_t* cidx  = csb + BATCH * CAP;                         // BATCH*CAP
  uint32_t* pidx  = cidx + BATCH * CAP;                        // BATCH*MAXDET
  uint32_t* pok   = pidx + BATCH * MAXDET;                     // BATCH*MAXDET

  zero_kernel<<<(BATCH * NBINS + 255) / 256, 256, 0, stream>>>(ghist, ctr, Tb);
  scores_kernel<<<(BN + 255) / 256, 256, 0, stream>>>(cls, ws_scores, ghist, N, BN);
  thresh_kernel<<<BATCH, 256, 0, stream>>>(ghist, Tb);
  dim3 cgrid((N + 1023) / 1024, BATCH);
  compact_kernel<<<cgrid, 1024, 0, stream>>>(ws_scores, Tb, ctr, csb, cidx, N);
  nms_kernel<<<BATCH, 256, 0, stream>>>(box, csb, cidx, ctr, pidx, pok, N);
  out_kernel<<<(BATCH * MAXDET + 255) / 256, 256, 0, stream>>>(box, cls, pidx, pok,
                                                               (float*)d_out, N);
}

// Round 5
// 177.516 us; speedup vs baseline: 8.9916x; 1.6227x over previous
//
#include <hip/hip_runtime.h>
#include <stdint.h>

#define BATCH 8
#define NCLS 80
#define MAXDET 100
#define CAP 1024
#define NBINS 10240          // keys 0..10036 (score 1.0) fit without clamping
#define CHUNKB 40            // 256 threads * 40 bins = 10240
#define BASEKEY (0x3D4CCCCDu >> 12)   // float bits of 0.05f >> 12

// ---------------- Kernel 0: zero per-call state ----------------
__global__ void zero_kernel(uint32_t* __restrict__ ghist, uint32_t* __restrict__ ctr,
                            uint32_t* __restrict__ Tb) {
  int i = blockIdx.x * blockDim.x + threadIdx.x;
  if (i < BATCH * NBINS) ghist[i] = 0;
  if (i < BATCH) { ctr[i] = 0; Tb[i] = NBINS; }
}

// ---------------- Kernel 1: scores = max softmax prob per row, + histogram ----------------
__global__ void scores_kernel(const float* __restrict__ cls,
                              float* __restrict__ scores,
                              uint32_t* __restrict__ ghist, int N, int BN) {
  int r = blockIdx.x * blockDim.x + threadIdx.x;
  if (r >= BN) return;
  const float4* p = (const float4*)(cls + (size_t)r * NCLS);
  float x[NCLS];
#pragma unroll
  for (int i = 0; i < NCLS / 4; i++) {
    float4 v = p[i];
    x[4 * i] = v.x; x[4 * i + 1] = v.y; x[4 * i + 2] = v.z; x[4 * i + 3] = v.w;
  }
  float m = x[0];
#pragma unroll
  for (int i = 1; i < NCLS; i++) m = fmaxf(m, x[i]);
  float r8[8];
#pragma unroll
  for (int j = 0; j < 8; j++) r8[j] = 0.0f;
#pragma unroll
  for (int i = 0; i < NCLS / 8; i++)
#pragma unroll
    for (int j = 0; j < 8; j++) r8[j] += expf(x[i * 8 + j] - m);
  float s = ((r8[0] + r8[1]) + (r8[2] + r8[3])) + ((r8[4] + r8[5]) + (r8[6] + r8[7]));
  float sc = 1.0f / s;
  scores[r] = sc;
  if (sc >= 0.05f) {
    int b = r / N;
    uint32_t key = (__float_as_uint(sc) >> 12) - BASEKEY;
    atomicAdd(&ghist[b * NBINS + key], 1u);
  }
}

// ---------------- Kernel 2: per-batch threshold bin (suffix count <= CAP) ----------------
__global__ __launch_bounds__(256)
void thresh_kernel(const uint32_t* __restrict__ ghist, uint32_t* __restrict__ Tb) {
  __shared__ uint32_t chs[256];
  const int b = blockIdx.x;
  const int tid = threadIdx.x;
  const uint32_t* h = ghist + b * NBINS;
  uint32_t csum = 0;
#pragma unroll
  for (int j = 0; j < CHUNKB; j++) csum += h[tid * CHUNKB + j];
  chs[tid] = csum;
  __syncthreads();
  for (int off = 1; off < 256; off <<= 1) {
    uint32_t v = chs[tid];
    uint32_t add = (tid + off < 256) ? chs[tid + off] : 0u;
    __syncthreads();
    chs[tid] = v + add;
    __syncthreads();
  }
  uint32_t St = chs[tid];
  uint32_t Sprev = (tid > 0) ? chs[tid - 1] : 0xFFFFFFFFu;
  if (St <= CAP && (tid == 0 || Sprev > CAP)) {
    int T = 0;
    if (tid != 0) {
      uint32_t cum = St;
      int lo = (tid - 1) * CHUNKB;
      T = lo;
      for (int bb = tid * CHUNKB - 1; bb >= lo; bb--) {
        uint32_t nb = cum + h[bb];
        if (nb > CAP) { T = bb + 1; break; }
        cum = nb;
        if (bb == lo) T = lo;
      }
    }
    Tb[b] = (uint32_t)T;
  }
}

// ---------------- Kernel 3: hierarchical compact (1 atomic per block) ----------------
__global__ __launch_bounds__(1024)
void compact_kernel(const float* __restrict__ scores,
                    const uint32_t* __restrict__ Tb,
                    uint32_t* __restrict__ ctr,
                    uint32_t* __restrict__ csb, uint32_t* __restrict__ cidx,
                    int N) {
  __shared__ uint32_t wbase[16];
  __shared__ uint32_t blkbase;
  const int b = blockIdx.y;
  const int i = blockIdx.x * 1024 + threadIdx.x;
  const int lane = threadIdx.x & 63, wid = threadIdx.x >> 6;

  bool q = false;
  float s = 0.f;
  if (i < N) {
    s = scores[(size_t)b * N + i];
    if (s >= 0.05f) {
      uint32_t key = (__float_as_uint(s) >> 12) - BASEKEY;
      q = key >= Tb[b];
    }
  }
  unsigned long long mask = __ballot(q);
  uint32_t wcnt = (uint32_t)__popcll(mask);
  uint32_t lpre = (uint32_t)__popcll(mask & ((1ULL << lane) - 1ULL));
  if (lane == 0) wbase[wid] = wcnt;
  __syncthreads();
  if (threadIdx.x == 0) {
    uint32_t tot = 0;
#pragma unroll
    for (int w = 0; w < 16; w++) { uint32_t c = wbase[w]; wbase[w] = tot; tot += c; }
    blkbase = tot ? atomicAdd(&ctr[b], tot) : 0u;
  }
  __syncthreads();
  if (q) {
    uint32_t slot = blkbase + wbase[wid] + lpre;
    if (slot < CAP) {
      csb[b * CAP + slot] = __float_as_uint(s);
      cidx[b * CAP + slot] = (uint32_t)i;
    }
  }
}

// ---------------- Kernel 4: sort + accepted-list greedy NMS ----------------
// Sort candidates by (score_bits, ~idx) desc (bitonic, LDS). Then walk in
// sorted order on ONE wave: candidate c is accepted iff no earlier ACCEPTED
// box has IoU > thr with it (suppression only ever comes from picks).
// Per-lane state: 4 floats (own candidate box) -> no spill.
__global__ __launch_bounds__(256, 1)
void nms_kernel(const float* __restrict__ box,
                const uint32_t* __restrict__ csb, const uint32_t* __restrict__ cidx,
                const uint32_t* __restrict__ ctr,
                uint32_t* __restrict__ pick_idx, uint32_t* __restrict__ pick_ok, int N) {
  __shared__ unsigned long long sk[CAP];
  __shared__ float sbox[CAP][4];
  __shared__ uint32_t sidx[CAP];
  __shared__ float accb[MAXDET][4];

  const int b = blockIdx.x;
  const int tid = threadIdx.x;
  uint32_t nc = ctr[b]; if (nc > CAP) nc = CAP;

  // load keys (0 = empty; real keys nonzero since score bits >= 0.05f bits)
#pragma unroll
  for (int q = 0; q < CAP / 256; q++) {
    int s = tid + q * 256;
    unsigned long long k = 0ULL;
    if (s < (int)nc)
      k = ((unsigned long long)csb[b * CAP + s] << 32) |
          (unsigned long long)(cidx[b * CAP + s] ^ 0xFFFFFFFFu);
    sk[s] = k;
  }
  __syncthreads();

  // bitonic sort, descending
  for (int k = 2; k <= CAP; k <<= 1) {
    for (int j = k >> 1; j > 0; j >>= 1) {
#pragma unroll
      for (int q = 0; q < CAP / 256; q++) {
        int i = tid + q * 256;
        int ixj = i ^ j;
        if (ixj > i) {
          unsigned long long a = sk[i], c = sk[ixj];
          if (((i & k) == 0) ? (a < c) : (a > c)) { sk[i] = c; sk[ixj] = a; }
        }
      }
      __syncthreads();
    }
  }

  // gather boxes of sorted candidates into LDS (corner-interp xywh form)
#pragma unroll
  for (int q = 0; q < CAP / 256; q++) {
    int s = tid + q * 256;
    unsigned long long k = sk[s];
    uint32_t idx = (uint32_t)k ^ 0xFFFFFFFFu;
    sidx[s] = idx;
    if (k != 0ULL) {
      const float4 f = *(const float4*)(box + ((size_t)b * N + idx) * 4);
      sbox[s][0] = f.x; sbox[s][1] = f.y; sbox[s][2] = f.z - f.x; sbox[s][3] = f.w - f.y;
    } else {
      sbox[s][0] = 0.f; sbox[s][1] = 0.f; sbox[s][2] = 0.f; sbox[s][3] = 0.f;
    }
  }
  __syncthreads();
  if (tid >= 64) return;   // walk is wave0-only; no barriers below

  const int lane = tid;
  uint32_t* pidx = pick_idx + b * MAXDET;
  uint32_t* pok  = pick_ok  + b * MAXDET;

  int nacc = 0;
  for (int cursor = 0; cursor < (int)nc && nacc < MAXDET; cursor += 64) {
    const int c = cursor + lane;
    bool alive = (c < (int)nc);
    float c0 = 0.f, c1 = 0.f, c2 = 0.f, c3 = 0.f;
    uint32_t myidx = 0;
    if (alive) {
      c0 = sbox[c][0]; c1 = sbox[c][1]; c2 = sbox[c][2]; c3 = sbox[c][3];
      myidx = sidx[c];
    }
    const float area_b = (c2 - c0) * (c3 - c1);

    // test chunk vs all accepted so far (lane-uniform LDS broadcast reads)
    for (int a = 0; a < nacc; a++) {
      float a_r = accb[a][0], b_r = accb[a][1], cc_r = accb[a][2], d_r = accb[a][3];
      float area_r = (cc_r - a_r) * (d_r - b_r);
      float ih = fmaxf(0.f, fminf(cc_r, c2) - fmaxf(a_r, c0));
      float iw = fmaxf(0.f, fminf(d_r, c3) - fmaxf(b_r, c1));
      float inter = ih * iw;
      float uni = area_r + area_b - inter;
      bool okk = (area_r > 0.f) && (area_b > 0.f) && (uni > 0.f);
      float iou = okk ? (inter / uni) : 0.f;
      if (iou > 0.5f) alive = false;
    }

    // serial accept within chunk
    unsigned long long am = __ballot(alive);
    while (am != 0ULL && nacc < MAXDET) {
      int L = (int)(__ffsll(am) - 1);
      float r0 = __shfl(c0, L), r1 = __shfl(c1, L);
      float r2 = __shfl(c2, L), r3 = __shfl(c3, L);
      uint32_t ridx = (uint32_t)__shfl((int)myidx, L);
      if (lane == 0) {
        pidx[nacc] = ridx; pok[nacc] = 1;
        accb[nacc][0] = r0; accb[nacc][1] = r1;
        accb[nacc][2] = r2; accb[nacc][3] = r3;
      }
      // drain LDS write before future broadcast reads (wave-synchronous)
      asm volatile("s_waitcnt lgkmcnt(0)" ::: "memory");
      if (lane == L) alive = false;
      if (alive) {
        float area_r = (r2 - r0) * (r3 - r1);
        float ih = fmaxf(0.f, fminf(r2, c2) - fmaxf(r0, c0));
        float iw = fmaxf(0.f, fminf(r3, c3) - fmaxf(r1, c1));
        float inter = ih * iw;
        float uni = area_r + area_b - inter;
        bool okk = (area_r > 0.f) && (area_b > 0.f) && (uni > 0.f);
        float iou = okk ? (inter / uni) : 0.f;
        if (iou > 0.5f) alive = false;
      }
      am = __ballot(alive);
      nacc++;
    }
  }

  if (lane == 0)
    for (int mm = nacc; mm < MAXDET; mm++) { pidx[mm] = 0; pok[mm] = 0; }
}

// ---------------- Kernel 5: gather outputs ----------------
__global__ void out_kernel(const float* __restrict__ box, const float* __restrict__ cls,
                           const uint32_t* __restrict__ pidx, const uint32_t* __restrict__ pok,
                           float* __restrict__ out, int N) {
  int r = blockIdx.x * blockDim.x + threadIdx.x;
  if (r >= BATCH * MAXDET) return;
  int b = r / MAXDET;
  float* boxes_out  = out;
  float* clsidx_out = out + BATCH * MAXDET * 4;
  float* cls_out    = out + BATCH * MAXDET * 4 + BATCH * MAXDET;

  uint32_t ok = pok[r];
  uint32_t idx = pidx[r];
  if (!ok) {
    boxes_out[r * 4 + 0] = 0.f; boxes_out[r * 4 + 1] = 0.f;
    boxes_out[r * 4 + 2] = 0.f; boxes_out[r * 4 + 3] = 0.f;
    clsidx_out[r] = 0.f;
    for (int j = 0; j < NCLS; j++) cls_out[r * NCLS + j] = 0.f;
    return;
  }
  const float4 f = *(const float4*)(box + ((size_t)b * N + idx) * 4);
  boxes_out[r * 4 + 0] = f.x;
  boxes_out[r * 4 + 1] = f.y;
  boxes_out[r * 4 + 2] = f.z - f.x;
  boxes_out[r * 4 + 3] = f.w - f.y;

  const float4* p = (const float4*)(cls + ((size_t)b * N + idx) * NCLS);
  float x[NCLS];
#pragma unroll
  for (int i = 0; i < NCLS / 4; i++) {
    float4 v = p[i];
    x[4 * i] = v.x; x[4 * i + 1] = v.y; x[4 * i + 2] = v.z; x[4 * i + 3] = v.w;
  }
  float m = x[0];
#pragma unroll
  for (int i = 1; i < NCLS; i++) m = fmaxf(m, x[i]);
  float e[NCLS];
#pragma unroll
  for (int i = 0; i < NCLS; i++) e[i] = expf(x[i] - m);
  float r8[8];
#pragma unroll
  for (int j = 0; j < 8; j++) r8[j] = 0.0f;
#pragma unroll
  for (int i = 0; i < NCLS / 8; i++)
#pragma unroll
    for (int j = 0; j < 8; j++) r8[j] += e[i * 8 + j];
  float s = ((r8[0] + r8[1]) + (r8[2] + r8[3])) + ((r8[4] + r8[5]) + (r8[6] + r8[7]));

  float best = -1.f; int bi = 0;
  for (int j = 0; j < NCLS; j++) {
    float pj = e[j] / s;
    cls_out[r * NCLS + j] = pj;
    if (pj > best) { best = pj; bi = j; }
  }
  clsidx_out[r] = (float)bi;
}

extern "C" void kernel_launch(void* const* d_in, const int* in_sizes, int n_in,
                              void* d_out, int out_size, void* d_ws, size_t ws_size,
                              hipStream_t stream) {
  (void)n_in; (void)out_size; (void)ws_size;
  const float* box = (const float*)d_in[0];
  const float* cls = (const float*)d_in[1];
  const int N = in_sizes[0] / (BATCH * 4);
  const int BN = BATCH * N;

  float*    ws_scores = (float*)d_ws;                          // BN floats
  uint32_t* ghist = (uint32_t*)(ws_scores + (size_t)BN);       // BATCH*NBINS
  uint32_t* ctr   = ghist + BATCH * NBINS;                     // BATCH
  uint32_t* Tb    = ctr + BATCH;                               // BATCH
  uint32_t* csb   = Tb + BATCH;                                // BATCH*CAP
  uint32_t* cidx  = csb + BATCH * CAP;                         // BATCH*CAP
  uint32_t* pidx  = cidx + BATCH * CAP;                        // BATCH*MAXDET
  uint32_t* pok   = pidx + BATCH * MAXDET;                     // BATCH*MAXDET

  zero_kernel<<<(BATCH * NBINS + 255) / 256, 256, 0, stream>>>(ghist, ctr, Tb);
  scores_kernel<<<(BN + 255) / 256, 256, 0, stream>>>(cls, ws_scores, ghist, N, BN);
  thresh_kernel<<<BATCH, 256, 0, stream>>>(ghist, Tb);
  dim3 cgrid((N + 1023) / 1024, BATCH);
  compact_kernel<<<cgrid, 1024, 0, stream>>>(ws_scores, Tb, ctr, csb, cidx, N);
  nms_kernel<<<BATCH, 256, 0, stream>>>(box, csb, cidx, ctr, pidx, pok, N);
  out_kernel<<<(BATCH * MAXDET + 255) / 256, 256, 0, stream>>>(box, cls, pidx, pok,
                                                               (float*)d_out, N);
}